// Round 1
// baseline (558.590 us; speedup 1.0000x reference)
//
#include <hip/hip_runtime.h>
#include <hip/hip_bf16.h>

// ---------------- problem constants ----------------
#define D_DIM 2048
#define HE_DIM 1024
#define E_NUM 8
#define T_NUM 4096
#define TK_NUM 8192           // T * K (top-2)
#define TILE 128              // GEMM M/N tile
#define BK 32                 // GEMM K tile (one 16x16x32 MFMA deep)
#define MAXROWS 9216          // TK + E*TILE padding
#define MAXMT 72              // max M-tiles: 64 + 8

// meta (int) layout in workspace
#define M_CNT 0               // [8] per-expert token count
#define M_FILL 8              // [8] atomic fill cursor
#define M_OFF 16              // [8] padded row base per expert
#define M_NMT 24              // [1] number of m-tiles
#define M_TE 32               // [72] m-tile -> expert
#define M_TB 104              // [72] m-tile -> global row base

typedef unsigned short u16;
typedef __attribute__((ext_vector_type(8))) short bf16x8;  // 8 bf16 in 4 VGPRs
typedef __attribute__((ext_vector_type(4))) float f32x4;

// workspace offsets (bytes)
#define OFF_XB   ((size_t)0)                                   // [T][D] bf16  16 MB
#define OFF_WUPB (OFF_XB + (size_t)T_NUM * D_DIM * 2)          // [E][HE][D] bf16 32 MB
#define OFF_WDNB (OFF_WUPB + (size_t)E_NUM * HE_DIM * D_DIM * 2) // [E][D][HE] bf16 32 MB
#define OFF_H    (OFF_WDNB + (size_t)E_NUM * D_DIM * HE_DIM * 2) // [MAXROWS][HE] bf16 18 MB
#define OFF_SCR  (OFF_H + (size_t)MAXROWS * HE_DIM * 2)        // [TK] f32 slot score
#define OFF_EIDX (OFF_SCR + (size_t)TK_NUM * 4)                // [TK] int slot expert
#define OFF_RT   (OFF_EIDX + (size_t)TK_NUM * 4)               // [MAXROWS] int row->token
#define OFF_RS   (OFF_RT + (size_t)MAXROWS * 4)                // [MAXROWS] f32 row score
#define OFF_META (OFF_RS + (size_t)MAXROWS * 4)                // ints

__device__ __forceinline__ u16 f2bf(float f) {
  unsigned u = __float_as_uint(f);
  u += 0x7FFFu + ((u >> 16) & 1u);   // round-to-nearest-even
  return (u16)(u >> 16);
}

__device__ __forceinline__ void gload16(const void* g, void* l) {
  // async global->LDS, 16B per lane; LDS dest = wave-uniform base + lane*16
  __builtin_amdgcn_global_load_lds((const __attribute__((address_space(1))) void*)g,
                                   (__attribute__((address_space(3))) void*)l,
                                   16, 0, 0);
}

// ---------------- init: meta zero, rows poisoned to "padding" ----------------
__global__ void k_init(int* __restrict__ meta, int* __restrict__ rows_token,
                       float* __restrict__ rowscore) {
  int i = blockIdx.x * blockDim.x + threadIdx.x;
  if (i < 32) meta[i] = 0;
  if (i < MAXROWS) { rows_token[i] = -1; rowscore[i] = 0.0f; }
}

__global__ void k_zero(float4* __restrict__ p, int n4) {
  int i = blockIdx.x * blockDim.x + threadIdx.x;
  int st = gridDim.x * blockDim.x;
  float4 z = make_float4(0.f, 0.f, 0.f, 0.f);
  for (; i < n4; i += st) p[i] = z;
}

// ---------------- f32 -> bf16 weight conversion ----------------
__global__ void k_cvt(const float4* __restrict__ src, ushort4* __restrict__ dst, int n4) {
  int i = blockIdx.x * blockDim.x + threadIdx.x;
  int st = gridDim.x * blockDim.x;
  for (; i < n4; i += st) {
    float4 v = src[i];
    ushort4 o;
    o.x = f2bf(v.x); o.y = f2bf(v.y); o.z = f2bf(v.z); o.w = f2bf(v.w);
    dst[i] = o;
  }
}

// ---------------- gate: logits, top-2, softmax, counts; also x->bf16 ----------------
__global__ __launch_bounds__(256) void k_gate(
    const float* __restrict__ x, const float* __restrict__ Wg1,
    const float* __restrict__ Wg2, u16* __restrict__ xb,
    int* __restrict__ eidx, float* __restrict__ scr, int* __restrict__ meta) {
  int w = threadIdx.x >> 6;
  int lane = threadIdx.x & 63;
  int t = blockIdx.x * 4 + w;
  const float* xr = x + (size_t)t * D_DIM;
  float acc[E_NUM];
#pragma unroll
  for (int e = 0; e < E_NUM; ++e) acc[e] = 0.f;
#pragma unroll 4
  for (int i = 0; i < D_DIM / 64; ++i) {
    int d = lane + i * 64;
    float xv = xr[d];
    xb[(size_t)t * D_DIM + d] = f2bf(xv);
#pragma unroll
    for (int e = 0; e < E_NUM; ++e) acc[e] += xv * Wg1[e * D_DIM + d];
  }
#pragma unroll
  for (int e = 0; e < E_NUM; ++e) {
    float v = acc[e];
#pragma unroll
    for (int off = 32; off; off >>= 1) v += __shfl_xor(v, off, 64);
    acc[e] = v;
  }
  if (lane == 0) {
    float l1[E_NUM], lg[E_NUM];
#pragma unroll
    for (int e = 0; e < E_NUM; ++e) l1[e] = tanhf(acc[e]);
#pragma unroll
    for (int i = 0; i < E_NUM; ++i) {
      float s = 0.f;
#pragma unroll
      for (int e = 0; e < E_NUM; ++e) s += l1[e] * Wg2[i * E_NUM + e];
      lg[i] = s;
    }
    // stable top-2 (lowest index wins ties, like jax.lax.top_k)
    int i0 = 0; float v0 = lg[0];
#pragma unroll
    for (int i = 1; i < E_NUM; ++i) if (lg[i] > v0) { v0 = lg[i]; i0 = i; }
    int i1 = -1; float v1 = -3.4e38f;
#pragma unroll
    for (int i = 0; i < E_NUM; ++i) if (i != i0 && lg[i] > v1) { v1 = lg[i]; i1 = i; }
    float e1 = __expf(v1 - v0);
    float s0 = 1.f / (1.f + e1);
    float s1 = e1 * s0;
    eidx[t * 2] = i0; eidx[t * 2 + 1] = i1;
    scr[t * 2] = s0;  scr[t * 2 + 1] = s1;
    atomicAdd(&meta[M_CNT + i0], 1);
    atomicAdd(&meta[M_CNT + i1], 1);
  }
}

// ---------------- offsets + tile map (tiny, single thread) ----------------
__global__ void k_offsets(int* __restrict__ meta) {
  if (threadIdx.x == 0 && blockIdx.x == 0) {
    int base = 0, mt = 0;
    for (int e = 0; e < E_NUM; ++e) {
      meta[M_OFF + e] = base;
      int tiles = (meta[M_CNT + e] + TILE - 1) / TILE;
      for (int i = 0; i < tiles; ++i) {
        meta[M_TE + mt] = e;
        meta[M_TB + mt] = base + i * TILE;
        ++mt;
      }
      base += tiles * TILE;
    }
    meta[M_NMT] = mt;
  }
}

// ---------------- compaction: (t,k) -> row ----------------
__global__ void k_assign(const int* __restrict__ eidx, const float* __restrict__ scr,
                         int* __restrict__ meta, int* __restrict__ rows_token,
                         float* __restrict__ rowscore) {
  int i = blockIdx.x * blockDim.x + threadIdx.x;
  if (i >= TK_NUM) return;
  int e = eidx[i];
  int pos = atomicAdd(&meta[M_FILL + e], 1);
  int r = meta[M_OFF + e] + pos;
  rows_token[r] = i >> 1;
  rowscore[r] = scr[i];
}

// ---------------- grouped up-GEMM: h = silu(Xg @ Wup[e]^T + bup[e]) ----------------
__global__ __launch_bounds__(256) void k_up(
    const u16* __restrict__ xb, const u16* __restrict__ wupb,
    const float* __restrict__ bup, const int* __restrict__ meta,
    const int* __restrict__ rows_token, u16* __restrict__ hbuf) {
  const int mt = blockIdx.y;
  if (mt >= meta[M_NMT]) return;
  const int e = meta[M_TE + mt];
  const int mbase = meta[M_TB + mt];
  const int nt = blockIdx.x;

  __shared__ u16 As[TILE * BK];
  __shared__ u16 Bs[TILE * BK];

  const int tid = threadIdx.x;
  const int lane = tid & 63;
  const int w = tid >> 6;
  const int ar0 = tid >> 2;                 // staged row for chunk tid
  const int cb = (tid & 3) * 8;             // k-offset (elements) within row
  int tok0 = rows_token[mbase + ar0];      if (tok0 < 0) tok0 = 0;
  int tok1 = rows_token[mbase + ar0 + 64]; if (tok1 < 0) tok1 = 0;
  const u16* ga0 = xb + (size_t)tok0 * D_DIM + cb;
  const u16* ga1 = xb + (size_t)tok1 * D_DIM + cb;
  const u16* gb0 = wupb + ((size_t)e * HE_DIM + nt * TILE + ar0) * D_DIM + cb;
  const u16* gb1 = gb0 + (size_t)64 * D_DIM;
  u16* lA0 = As + tid * 8;
  u16* lA1 = lA0 + 2048;
  u16* lB0 = Bs + tid * 8;
  u16* lB1 = lB0 + 2048;

  const int wm = (w & 1) * 64;
  const int wn = (w >> 1) * 64;
  const int quad = lane >> 4;
  const int l16 = lane & 15;
  const u16* pa = As + (wm + l16) * BK + quad * 8;
  const u16* pb = Bs + (wn + l16) * BK + quad * 8;

  f32x4 acc[4][4] = {};

  for (int k0 = 0; k0 < D_DIM; k0 += BK) {
    gload16(ga0 + k0, lA0);
    gload16(ga1 + k0, lA1);
    gload16(gb0 + k0, lB0);
    gload16(gb1 + k0, lB1);
    __syncthreads();
    bf16x8 af[4], bfr[4];
#pragma unroll
    for (int i = 0; i < 4; ++i) {
      af[i]  = *(const bf16x8*)(pa + i * 16 * BK);
      bfr[i] = *(const bf16x8*)(pb + i * 16 * BK);
    }
#pragma unroll
    for (int mi = 0; mi < 4; ++mi)
#pragma unroll
      for (int ni = 0; ni < 4; ++ni)
        acc[mi][ni] = __builtin_amdgcn_mfma_f32_16x16x32_bf16(af[mi], bfr[ni], acc[mi][ni], 0, 0, 0);
    __syncthreads();
  }

#pragma unroll
  for (int mi = 0; mi < 4; ++mi) {
    const int m = wm + mi * 16 + quad * 4;
#pragma unroll
    for (int ni = 0; ni < 4; ++ni) {
      const int ng = nt * TILE + wn + ni * 16 + l16;
      const float bias = bup[e * HE_DIM + ng];
#pragma unroll
      for (int r = 0; r < 4; ++r) {
        float v = acc[mi][ni][r] + bias;
        v = v / (1.0f + __expf(-v));     // silu
        hbuf[(size_t)(mbase + m + r) * HE_DIM + ng] = f2bf(v);
      }
    }
  }
}

// ---------------- grouped down-GEMM: out[tok] += score * (h @ Wdown[e]^T + bdown[e]) ----------------
__global__ __launch_bounds__(256) void k_down(
    const u16* __restrict__ hbuf, const u16* __restrict__ wdnb,
    const float* __restrict__ bdown, const int* __restrict__ meta,
    const int* __restrict__ rows_token, const float* __restrict__ rowscore,
    float* __restrict__ out) {
  const int mt = blockIdx.y;
  if (mt >= meta[M_NMT]) return;
  const int e = meta[M_TE + mt];
  const int mbase = meta[M_TB + mt];
  const int nt = blockIdx.x;

  __shared__ u16 As[TILE * BK];
  __shared__ u16 Bs[TILE * BK];

  const int tid = threadIdx.x;
  const int lane = tid & 63;
  const int w = tid >> 6;
  const int ar0 = tid >> 2;
  const int cb = (tid & 3) * 8;
  const u16* ga0 = hbuf + (size_t)(mbase + ar0) * HE_DIM + cb;
  const u16* ga1 = ga0 + (size_t)64 * HE_DIM;
  const u16* gb0 = wdnb + ((size_t)e * D_DIM + nt * TILE + ar0) * HE_DIM + cb;
  const u16* gb1 = gb0 + (size_t)64 * HE_DIM;
  u16* lA0 = As + tid * 8;
  u16* lA1 = lA0 + 2048;
  u16* lB0 = Bs + tid * 8;
  u16* lB1 = lB0 + 2048;

  const int wm = (w & 1) * 64;
  const int wn = (w >> 1) * 64;
  const int quad = lane >> 4;
  const int l16 = lane & 15;
  const u16* pa = As + (wm + l16) * BK + quad * 8;
  const u16* pb = Bs + (wn + l16) * BK + quad * 8;

  f32x4 acc[4][4] = {};

  for (int k0 = 0; k0 < HE_DIM; k0 += BK) {
    gload16(ga0 + k0, lA0);
    gload16(ga1 + k0, lA1);
    gload16(gb0 + k0, lB0);
    gload16(gb1 + k0, lB1);
    __syncthreads();
    bf16x8 af[4], bfr[4];
#pragma unroll
    for (int i = 0; i < 4; ++i) {
      af[i]  = *(const bf16x8*)(pa + i * 16 * BK);
      bfr[i] = *(const bf16x8*)(pb + i * 16 * BK);
    }
#pragma unroll
    for (int mi = 0; mi < 4; ++mi)
#pragma unroll
      for (int ni = 0; ni < 4; ++ni)
        acc[mi][ni] = __builtin_amdgcn_mfma_f32_16x16x32_bf16(af[mi], bfr[ni], acc[mi][ni], 0, 0, 0);
    __syncthreads();
  }

#pragma unroll
  for (int mi = 0; mi < 4; ++mi) {
    const int m = wm + mi * 16 + quad * 4;
#pragma unroll
    for (int r = 0; r < 4; ++r) {
      const int rg = mbase + m + r;
      const int tok = rows_token[rg];
      const float sc = rowscore[rg];
      if (tok < 0) continue;             // padding row
#pragma unroll
      for (int ni = 0; ni < 4; ++ni) {
        const int ng = nt * TILE + wn + ni * 16 + l16;
        float v = (acc[mi][ni][r] + bdown[e * D_DIM + ng]) * sc;
        atomicAdd(&out[(size_t)tok * D_DIM + ng], v);
      }
    }
  }
}

// ---------------- launcher ----------------
extern "C" void kernel_launch(void* const* d_in, const int* in_sizes, int n_in,
                              void* d_out, int out_size, void* d_ws, size_t ws_size,
                              hipStream_t stream) {
  const float* x     = (const float*)d_in[0];
  const float* Wg1   = (const float*)d_in[1];
  const float* Wg2   = (const float*)d_in[2];
  const float* Wup   = (const float*)d_in[3];
  const float* bup   = (const float*)d_in[4];
  const float* Wdown = (const float*)d_in[5];
  const float* bdown = (const float*)d_in[6];
  float* out = (float*)d_out;

  char* ws = (char*)d_ws;
  u16*   xb         = (u16*)(ws + OFF_XB);
  u16*   wupb       = (u16*)(ws + OFF_WUPB);
  u16*   wdnb       = (u16*)(ws + OFF_WDNB);
  u16*   hbuf       = (u16*)(ws + OFF_H);
  float* scr        = (float*)(ws + OFF_SCR);
  int*   eidx       = (int*)(ws + OFF_EIDX);
  int*   rows_token = (int*)(ws + OFF_RT);
  float* rowscore   = (float*)(ws + OFF_RS);
  int*   meta       = (int*)(ws + OFF_META);

  k_init<<<(MAXROWS + 255) / 256, 256, 0, stream>>>(meta, rows_token, rowscore);
  k_zero<<<2048, 256, 0, stream>>>((float4*)out, T_NUM * D_DIM / 4);
  k_cvt<<<4096, 256, 0, stream>>>((const float4*)Wup, (ushort4*)wupb,
                                  E_NUM * HE_DIM * D_DIM / 4);
  k_cvt<<<4096, 256, 0, stream>>>((const float4*)Wdown, (ushort4*)wdnb,
                                  E_NUM * D_DIM * HE_DIM / 4);
  k_gate<<<T_NUM / 4, 256, 0, stream>>>(x, Wg1, Wg2, xb, eidx, scr, meta);
  k_offsets<<<1, 64, 0, stream>>>(meta);
  k_assign<<<TK_NUM / 256, 256, 0, stream>>>(eidx, scr, meta, rows_token, rowscore);
  k_up<<<dim3(HE_DIM / TILE, MAXMT), 256, 0, stream>>>(xb, wupb, bup, meta, rows_token, hbuf);
  k_down<<<dim3(D_DIM / TILE, MAXMT), 256, 0, stream>>>(hbuf, wdnb, bdown, meta,
                                                        rows_token, rowscore, out);
}

// Round 2
// 485.845 us; speedup vs baseline: 1.1497x; 1.1497x over previous
//
#include <hip/hip_runtime.h>
#include <hip/hip_bf16.h>

// ---------------- problem constants ----------------
#define D_DIM 2048
#define HE_DIM 1024
#define E_NUM 8
#define T_NUM 4096
#define TK_NUM 8192           // T * K (top-2)
#define TILE 128              // GEMM M/N tile
#define BK 64                 // GEMM K tile (two 16x16x32 MFMA deep -> 32 MFMA/barrier)
#define MAXROWS 9216          // TK + E*TILE padding
#define MAXMT 72              // max M-tiles: 64 + 8

// meta (int) layout in workspace
#define M_CNT 0               // [8] per-expert token count
#define M_FILL 8              // [8] atomic fill cursor
#define M_OFF 16              // [8] padded row base per expert
#define M_NMT 24              // [1] number of m-tiles
#define M_TE 32               // [72] m-tile -> expert
#define M_TB 104              // [72] m-tile -> global row base

typedef unsigned short u16;
typedef __attribute__((ext_vector_type(8))) short bf16x8;  // 8 bf16 in 4 VGPRs
typedef __attribute__((ext_vector_type(4))) float f32x4;

// workspace offsets (bytes)
// xb [0,16M) and wupb [16M,48M) are dead after k_up; slot [T][2][D] bf16 (33.5M)
// overlaps them (k_down/k_combine run strictly after k_up on the stream).
#define OFF_XB   ((size_t)0)                                     // [T][D] bf16  16 MB
#define OFF_WUPB (OFF_XB + (size_t)T_NUM * D_DIM * 2)            // [E][HE][D] bf16 32 MB
#define OFF_SLOT ((size_t)0)                                     // [T][2][D] bf16 33.5 MB (overlap)
#define OFF_WDNB (OFF_WUPB + (size_t)E_NUM * HE_DIM * D_DIM * 2) // [E][D][HE] bf16 32 MB
#define OFF_H    (OFF_WDNB + (size_t)E_NUM * D_DIM * HE_DIM * 2) // [MAXROWS][HE] bf16 18.9 MB
#define OFF_SCR  (OFF_H + (size_t)MAXROWS * HE_DIM * 2)          // [TK] f32 slot score
#define OFF_EIDX (OFF_SCR + (size_t)TK_NUM * 4)                  // [TK] int slot expert
#define OFF_RT   (OFF_EIDX + (size_t)TK_NUM * 4)                 // [MAXROWS] int row->slot id
#define OFF_RS   (OFF_RT + (size_t)MAXROWS * 4)                  // [MAXROWS] f32 row score
#define OFF_META (OFF_RS + (size_t)MAXROWS * 4)                  // ints

__device__ __forceinline__ u16 f2bf(float f) {
  unsigned u = __float_as_uint(f);
  u += 0x7FFFu + ((u >> 16) & 1u);   // round-to-nearest-even
  return (u16)(u >> 16);
}
__device__ __forceinline__ float bf_lo(unsigned u) { return __uint_as_float(u << 16); }
__device__ __forceinline__ float bf_hi(unsigned u) { return __uint_as_float(u & 0xFFFF0000u); }

__device__ __forceinline__ void gload16(const void* g, void* l) {
  // async global->LDS, 16B per lane; LDS dest = wave-uniform base + lane*16
  __builtin_amdgcn_global_load_lds((const __attribute__((address_space(1))) void*)g,
                                   (__attribute__((address_space(3))) void*)l,
                                   16, 0, 0);
}

// ---------------- init: meta zero, rows poisoned to "padding" ----------------
__global__ void k_init(int* __restrict__ meta, int* __restrict__ rows_slot,
                       float* __restrict__ rowscore) {
  int i = blockIdx.x * blockDim.x + threadIdx.x;
  if (i < 32) meta[i] = 0;
  if (i < MAXROWS) { rows_slot[i] = -1; rowscore[i] = 0.0f; }
}

// ---------------- f32 -> bf16 weight conversion ----------------
__global__ void k_cvt(const float4* __restrict__ src, ushort4* __restrict__ dst, int n4) {
  int i = blockIdx.x * blockDim.x + threadIdx.x;
  int st = gridDim.x * blockDim.x;
  for (; i < n4; i += st) {
    float4 v = src[i];
    ushort4 o;
    o.x = f2bf(v.x); o.y = f2bf(v.y); o.z = f2bf(v.z); o.w = f2bf(v.w);
    dst[i] = o;
  }
}

// ---------------- gate: logits, top-2, softmax, counts; also x->bf16 ----------------
__global__ __launch_bounds__(256) void k_gate(
    const float* __restrict__ x, const float* __restrict__ Wg1,
    const float* __restrict__ Wg2, u16* __restrict__ xb,
    int* __restrict__ eidx, float* __restrict__ scr, int* __restrict__ meta) {
  int w = threadIdx.x >> 6;
  int lane = threadIdx.x & 63;
  int t = blockIdx.x * 4 + w;
  const float* xr = x + (size_t)t * D_DIM;
  float acc[E_NUM];
#pragma unroll
  for (int e = 0; e < E_NUM; ++e) acc[e] = 0.f;
#pragma unroll 4
  for (int i = 0; i < D_DIM / 64; ++i) {
    int d = lane + i * 64;
    float xv = xr[d];
    xb[(size_t)t * D_DIM + d] = f2bf(xv);
#pragma unroll
    for (int e = 0; e < E_NUM; ++e) acc[e] += xv * Wg1[e * D_DIM + d];
  }
#pragma unroll
  for (int e = 0; e < E_NUM; ++e) {
    float v = acc[e];
#pragma unroll
    for (int off = 32; off; off >>= 1) v += __shfl_xor(v, off, 64);
    acc[e] = v;
  }
  if (lane == 0) {
    float l1[E_NUM], lg[E_NUM];
#pragma unroll
    for (int e = 0; e < E_NUM; ++e) l1[e] = tanhf(acc[e]);
#pragma unroll
    for (int i = 0; i < E_NUM; ++i) {
      float s = 0.f;
#pragma unroll
      for (int e = 0; e < E_NUM; ++e) s += l1[e] * Wg2[i * E_NUM + e];
      lg[i] = s;
    }
    // stable top-2 (lowest index wins ties, like jax.lax.top_k)
    int i0 = 0; float v0 = lg[0];
#pragma unroll
    for (int i = 1; i < E_NUM; ++i) if (lg[i] > v0) { v0 = lg[i]; i0 = i; }
    int i1 = -1; float v1 = -3.4e38f;
#pragma unroll
    for (int i = 0; i < E_NUM; ++i) if (i != i0 && lg[i] > v1) { v1 = lg[i]; i1 = i; }
    float e1 = __expf(v1 - v0);
    float s0 = 1.f / (1.f + e1);
    float s1 = e1 * s0;
    eidx[t * 2] = i0; eidx[t * 2 + 1] = i1;
    scr[t * 2] = s0;  scr[t * 2 + 1] = s1;
    atomicAdd(&meta[M_CNT + i0], 1);
    atomicAdd(&meta[M_CNT + i1], 1);
  }
}

// ---------------- offsets + tile map (tiny, single thread) ----------------
__global__ void k_offsets(int* __restrict__ meta) {
  if (threadIdx.x == 0 && blockIdx.x == 0) {
    int base = 0, mt = 0;
    for (int e = 0; e < E_NUM; ++e) {
      meta[M_OFF + e] = base;
      int tiles = (meta[M_CNT + e] + TILE - 1) / TILE;
      for (int i = 0; i < tiles; ++i) {
        meta[M_TE + mt] = e;
        meta[M_TB + mt] = base + i * TILE;
        ++mt;
      }
      base += tiles * TILE;
    }
    meta[M_NMT] = mt;
  }
}

// ---------------- compaction: (t,k) slot -> row ----------------
__global__ void k_assign(const int* __restrict__ eidx, const float* __restrict__ scr,
                         int* __restrict__ meta, int* __restrict__ rows_slot,
                         float* __restrict__ rowscore) {
  int i = blockIdx.x * blockDim.x + threadIdx.x;
  if (i >= TK_NUM) return;
  int e = eidx[i];
  int pos = atomicAdd(&meta[M_FILL + e], 1);
  int r = meta[M_OFF + e] + pos;
  rows_slot[r] = i;            // slot id (token = i>>1)
  rowscore[r] = scr[i];
}

// ---------------- grouped up-GEMM: h = silu(Xg @ Wup[e]^T + bup[e]) ----------------
// BK=64: 32 MFMA between barriers; XOR swizzle (on GLOBAL read addr) kills LDS
// bank conflicts while keeping the global_load_lds LDS destination linear.
__global__ __launch_bounds__(256) void k_up(
    const u16* __restrict__ xb, const u16* __restrict__ wupb,
    const float* __restrict__ bup, const int* __restrict__ meta,
    const int* __restrict__ rows_slot, u16* __restrict__ hbuf) {
  const int mt = blockIdx.y;
  if (mt >= meta[M_NMT]) return;
  const int e = meta[M_TE + mt];
  const int mbase = meta[M_TB + mt];
  const int nt = blockIdx.x;

  __shared__ u16 As[TILE * BK];
  __shared__ u16 Bs[TILE * BK];

  const int tid = threadIdx.x;
  const int lane = tid & 63;
  const int w = tid >> 6;
  const int r0 = tid >> 3;                               // staged row 0..31
  const int cb = (((tid & 7) ^ ((tid >> 3) & 7)) * 8);   // swizzled k-chunk

  const u16* gA[4];
  const u16* gB[4];
#pragma unroll
  for (int j = 0; j < 4; ++j) {
    int s = rows_slot[mbase + r0 + 32 * j]; if (s < 0) s = 0;
    gA[j] = xb + (size_t)(s >> 1) * D_DIM + cb;
    gB[j] = wupb + ((size_t)e * HE_DIM + nt * TILE + r0 + 32 * j) * D_DIM + cb;
  }
  u16* lA = As + tid * 8;
  u16* lB = Bs + tid * 8;

  const int wm = (w & 1) * 64;
  const int wn = (w >> 1) * 64;
  const int quad = lane >> 4;
  const int l16 = lane & 15;
  const int sw = l16 & 7;
  const u16* pa0 = As + (wm + l16) * BK;
  const u16* pb0 = Bs + (wn + l16) * BK;

  f32x4 acc[4][4] = {};

  for (int k0 = 0; k0 < D_DIM; k0 += BK) {
#pragma unroll
    for (int j = 0; j < 4; ++j) gload16(gA[j] + k0, lA + 2048 * j);
#pragma unroll
    for (int j = 0; j < 4; ++j) gload16(gB[j] + k0, lB + 2048 * j);
    __syncthreads();
#pragma unroll
    for (int h = 0; h < 2; ++h) {
      const int off = ((h * 4 + quad) ^ sw) * 8;
      bf16x8 af[4], bfr[4];
#pragma unroll
      for (int i = 0; i < 4; ++i) {
        af[i]  = *(const bf16x8*)(pa0 + i * 16 * BK + off);
        bfr[i] = *(const bf16x8*)(pb0 + i * 16 * BK + off);
      }
#pragma unroll
      for (int mi = 0; mi < 4; ++mi)
#pragma unroll
        for (int ni = 0; ni < 4; ++ni)
          acc[mi][ni] = __builtin_amdgcn_mfma_f32_16x16x32_bf16(af[mi], bfr[ni], acc[mi][ni], 0, 0, 0);
    }
    __syncthreads();
  }

#pragma unroll
  for (int mi = 0; mi < 4; ++mi) {
    const int m = wm + mi * 16 + quad * 4;
#pragma unroll
    for (int ni = 0; ni < 4; ++ni) {
      const int ng = nt * TILE + wn + ni * 16 + l16;
      const float bias = bup[e * HE_DIM + ng];
#pragma unroll
      for (int r = 0; r < 4; ++r) {
        float v = acc[mi][ni][r] + bias;
        v = v / (1.0f + __expf(-v));     // silu
        hbuf[(size_t)(mbase + m + r) * HE_DIM + ng] = f2bf(v);
      }
    }
  }
}

// ---------------- grouped down-GEMM: slot[s] = score * (h @ Wdown[e]^T + bdown[e]) ----------------
__global__ __launch_bounds__(256) void k_down(
    const u16* __restrict__ hbuf, const u16* __restrict__ wdnb,
    const float* __restrict__ bdown, const int* __restrict__ meta,
    const int* __restrict__ rows_slot, const float* __restrict__ rowscore,
    u16* __restrict__ slot) {
  const int mt = blockIdx.y;
  if (mt >= meta[M_NMT]) return;
  const int e = meta[M_TE + mt];
  const int mbase = meta[M_TB + mt];
  const int nt = blockIdx.x;

  __shared__ u16 As[TILE * BK];
  __shared__ u16 Bs[TILE * BK];

  const int tid = threadIdx.x;
  const int lane = tid & 63;
  const int w = tid >> 6;
  const int r0 = tid >> 3;
  const int cb = (((tid & 7) ^ ((tid >> 3) & 7)) * 8);

  const u16* gA[4];
  const u16* gB[4];
#pragma unroll
  for (int j = 0; j < 4; ++j) {
    gA[j] = hbuf + (size_t)(mbase + r0 + 32 * j) * HE_DIM + cb;
    gB[j] = wdnb + ((size_t)e * D_DIM + nt * TILE + r0 + 32 * j) * HE_DIM + cb;
  }
  u16* lA = As + tid * 8;
  u16* lB = Bs + tid * 8;

  const int wm = (w & 1) * 64;
  const int wn = (w >> 1) * 64;
  const int quad = lane >> 4;
  const int l16 = lane & 15;
  const int sw = l16 & 7;
  const u16* pa0 = As + (wm + l16) * BK;
  const u16* pb0 = Bs + (wn + l16) * BK;

  f32x4 acc[4][4] = {};

  for (int k0 = 0; k0 < HE_DIM; k0 += BK) {
#pragma unroll
    for (int j = 0; j < 4; ++j) gload16(gA[j] + k0, lA + 2048 * j);
#pragma unroll
    for (int j = 0; j < 4; ++j) gload16(gB[j] + k0, lB + 2048 * j);
    __syncthreads();
#pragma unroll
    for (int h = 0; h < 2; ++h) {
      const int off = ((h * 4 + quad) ^ sw) * 8;
      bf16x8 af[4], bfr[4];
#pragma unroll
      for (int i = 0; i < 4; ++i) {
        af[i]  = *(const bf16x8*)(pa0 + i * 16 * BK + off);
        bfr[i] = *(const bf16x8*)(pb0 + i * 16 * BK + off);
      }
#pragma unroll
      for (int mi = 0; mi < 4; ++mi)
#pragma unroll
        for (int ni = 0; ni < 4; ++ni)
          acc[mi][ni] = __builtin_amdgcn_mfma_f32_16x16x32_bf16(af[mi], bfr[ni], acc[mi][ni], 0, 0, 0);
    }
    __syncthreads();
  }

#pragma unroll
  for (int mi = 0; mi < 4; ++mi) {
    const int m = wm + mi * 16 + quad * 4;
#pragma unroll
    for (int r = 0; r < 4; ++r) {
      const int rg = mbase + m + r;
      const int s = rows_slot[rg];
      const float sc = rowscore[rg];
      if (s < 0) continue;               // padding row
      u16* dst = slot + (size_t)s * D_DIM;
#pragma unroll
      for (int ni = 0; ni < 4; ++ni) {
        const int ng = nt * TILE + wn + ni * 16 + l16;
        float v = (acc[mi][ni][r] + bdown[e * D_DIM + ng]) * sc;
        dst[ng] = f2bf(v);
      }
    }
  }
}

// ---------------- combine: out[t] = slot[t][0] + slot[t][1] (fully coalesced) ----------------
__global__ __launch_bounds__(256) void k_combine(const u16* __restrict__ slot,
                                                 float* __restrict__ out) {
  int i = blockIdx.x * blockDim.x + threadIdx.x;   // one 16B chunk (8 bf16) per thread
  int t = i >> 8;                                  // D/8 = 256 chunks per token
  int c = i & 255;
  const uint4* p0 = (const uint4*)(slot + (size_t)(t * 2) * D_DIM) + c;
  const uint4* p1 = (const uint4*)(slot + (size_t)(t * 2 + 1) * D_DIM) + c;
  uint4 a = *p0, b = *p1;
  float4 o0, o1;
  o0.x = bf_lo(a.x) + bf_lo(b.x);  o0.y = bf_hi(a.x) + bf_hi(b.x);
  o0.z = bf_lo(a.y) + bf_lo(b.y);  o0.w = bf_hi(a.y) + bf_hi(b.y);
  o1.x = bf_lo(a.z) + bf_lo(b.z);  o1.y = bf_hi(a.z) + bf_hi(b.z);
  o1.z = bf_lo(a.w) + bf_lo(b.w);  o1.w = bf_hi(a.w) + bf_hi(b.w);
  float4* po = (float4*)(out + (size_t)t * D_DIM) + c * 2;
  po[0] = o0;
  po[1] = o1;
}

// ---------------- launcher ----------------
extern "C" void kernel_launch(void* const* d_in, const int* in_sizes, int n_in,
                              void* d_out, int out_size, void* d_ws, size_t ws_size,
                              hipStream_t stream) {
  const float* x     = (const float*)d_in[0];
  const float* Wg1   = (const float*)d_in[1];
  const float* Wg2   = (const float*)d_in[2];
  const float* Wup   = (const float*)d_in[3];
  const float* bup   = (const float*)d_in[4];
  const float* Wdown = (const float*)d_in[5];
  const float* bdown = (const float*)d_in[6];
  float* out = (float*)d_out;

  char* ws = (char*)d_ws;
  u16*   xb         = (u16*)(ws + OFF_XB);
  u16*   wupb       = (u16*)(ws + OFF_WUPB);
  u16*   wdnb       = (u16*)(ws + OFF_WDNB);
  u16*   hbuf       = (u16*)(ws + OFF_H);
  u16*   slotbuf    = (u16*)(ws + OFF_SLOT);
  float* scr        = (float*)(ws + OFF_SCR);
  int*   eidx       = (int*)(ws + OFF_EIDX);
  int*   rows_slot  = (int*)(ws + OFF_RT);
  float* rowscore   = (float*)(ws + OFF_RS);
  int*   meta       = (int*)(ws + OFF_META);

  k_init<<<(MAXROWS + 255) / 256, 256, 0, stream>>>(meta, rows_slot, rowscore);
  k_cvt<<<4096, 256, 0, stream>>>((const float4*)Wup, (ushort4*)wupb,
                                  E_NUM * HE_DIM * D_DIM / 4);
  k_cvt<<<4096, 256, 0, stream>>>((const float4*)Wdown, (ushort4*)wdnb,
                                  E_NUM * D_DIM * HE_DIM / 4);
  k_gate<<<T_NUM / 4, 256, 0, stream>>>(x, Wg1, Wg2, xb, eidx, scr, meta);
  k_offsets<<<1, 64, 0, stream>>>(meta);
  k_assign<<<TK_NUM / 256, 256, 0, stream>>>(eidx, scr, meta, rows_slot, rowscore);
  k_up<<<dim3(HE_DIM / TILE, MAXMT), 256, 0, stream>>>(xb, wupb, bup, meta, rows_slot, hbuf);
  k_down<<<dim3(D_DIM / TILE, MAXMT), 256, 0, stream>>>(hbuf, wdnb, bdown, meta,
                                                        rows_slot, rowscore, slotbuf);
  k_combine<<<T_NUM * D_DIM / 8 / 256, 256, 0, stream>>>(slotbuf, out);
}

// Round 3
// 481.400 us; speedup vs baseline: 1.1603x; 1.0092x over previous
//
#include <hip/hip_runtime.h>
#include <hip/hip_bf16.h>

// ---------------- problem constants ----------------
#define D_DIM 2048
#define HE_DIM 1024
#define E_NUM 8
#define T_NUM 4096
#define TK_NUM 8192           // T * K (top-2)
#define TILE 128              // GEMM M/N tile
#define BK 64                 // GEMM K tile (two 16x16x32 MFMA deep -> 32 MFMA/barrier)
#define MAXROWS 9216          // TK + E*TILE padding
#define MAXMT 72              // max M-tiles: 64 + 8

// meta (int) layout in workspace
#define M_CNT 0               // [8] per-expert token count
#define M_FILL 8              // [8] atomic fill cursor
#define M_OFF 16              // [8] padded row base per expert
#define M_NMT 24              // [1] number of m-tiles
#define M_TE 32               // [72] m-tile -> expert
#define M_TB 104              // [72] m-tile -> global row base

typedef unsigned short u16;
typedef __attribute__((ext_vector_type(8))) short bf16x8;  // 8 bf16 in 4 VGPRs
typedef __attribute__((ext_vector_type(4))) float f32x4;

// workspace offsets (bytes)
// xb [0,16M) and wupb [16M,48M) are dead after k_up; slot [T][2][D] bf16 (33.5M)
// overlaps them (k_down/k_combine run strictly after k_up on the stream).
#define OFF_XB   ((size_t)0)                                     // [T][D] bf16  16 MB
#define OFF_WUPB (OFF_XB + (size_t)T_NUM * D_DIM * 2)            // [E][HE][D] bf16 32 MB
#define OFF_SLOT ((size_t)0)                                     // [T][2][D] bf16 33.5 MB (overlap)
#define OFF_WDNB (OFF_WUPB + (size_t)E_NUM * HE_DIM * D_DIM * 2) // [E][D][HE] bf16 32 MB
#define OFF_H    (OFF_WDNB + (size_t)E_NUM * D_DIM * HE_DIM * 2) // [MAXROWS][HE] bf16 18.9 MB
#define OFF_SCR  (OFF_H + (size_t)MAXROWS * HE_DIM * 2)          // [TK] f32 slot score
#define OFF_EIDX (OFF_SCR + (size_t)TK_NUM * 4)                  // [TK] int slot expert
#define OFF_RT   (OFF_EIDX + (size_t)TK_NUM * 4)                 // [MAXROWS] int row->slot id
#define OFF_RS   (OFF_RT + (size_t)MAXROWS * 4)                  // [MAXROWS] f32 row score
#define OFF_META (OFF_RS + (size_t)MAXROWS * 4)                  // ints

__device__ __forceinline__ u16 f2bf(float f) {
  unsigned u = __float_as_uint(f);
  u += 0x7FFFu + ((u >> 16) & 1u);   // round-to-nearest-even
  return (u16)(u >> 16);
}
__device__ __forceinline__ float bf_lo(unsigned u) { return __uint_as_float(u << 16); }
__device__ __forceinline__ float bf_hi(unsigned u) { return __uint_as_float(u & 0xFFFF0000u); }

__device__ __forceinline__ void gload16(const void* g, void* l) {
  // async global->LDS, 16B per lane; LDS dest = wave-uniform base + lane*16
  __builtin_amdgcn_global_load_lds((const __attribute__((address_space(1))) void*)g,
                                   (__attribute__((address_space(3))) void*)l,
                                   16, 0, 0);
}

// ---------------- init: meta zero, rows poisoned to "padding" ----------------
__global__ void k_init(int* __restrict__ meta, int* __restrict__ rows_slot,
                       float* __restrict__ rowscore) {
  int i = blockIdx.x * blockDim.x + threadIdx.x;
  if (i < 32) meta[i] = 0;
  if (i < MAXROWS) { rows_slot[i] = -1; rowscore[i] = 0.0f; }
}

// ---------------- f32 -> bf16 weight conversion (both weights, one launch) ----------------
__global__ void k_cvt2(const float4* __restrict__ s1, const float4* __restrict__ s2,
                       ushort4* __restrict__ d1, ushort4* __restrict__ d2, int n4) {
  int i = blockIdx.x * blockDim.x + threadIdx.x;
  int st = gridDim.x * blockDim.x;
  for (; i < 2 * n4; i += st) {
    const float4* s = (i < n4) ? s1 : s2;
    ushort4* d = (i < n4) ? d1 : d2;
    int j = (i < n4) ? i : i - n4;
    float4 v = s[j];
    ushort4 o;
    o.x = f2bf(v.x); o.y = f2bf(v.y); o.z = f2bf(v.z); o.w = f2bf(v.w);
    d[j] = o;
  }
}

// ---------------- gate: Wg1 staged in LDS, float4 x loads, fused x->bf16 ----------------
// 256 blocks x 256 threads; block stages Wg1 (64 KB f32) once, each wave does 4 tokens.
__global__ __launch_bounds__(256) void k_gate(
    const float4* __restrict__ x4, const float4* __restrict__ Wg1_4,
    const float* __restrict__ Wg2, ushort4* __restrict__ xb4,
    int* __restrict__ eidx, float* __restrict__ scr, int* __restrict__ meta) {
  __shared__ float4 wg1s[E_NUM * (D_DIM / 4)];   // 8*512*16B = 64 KB
  const int tid = threadIdx.x;
#pragma unroll
  for (int i = 0; i < 16; ++i) wg1s[tid + i * 256] = Wg1_4[tid + i * 256];
  __syncthreads();

  const int w = tid >> 6;
  const int lane = tid & 63;
  for (int j = 0; j < 4; ++j) {
    const int t = blockIdx.x * 16 + w * 4 + j;
    float acc[E_NUM];
#pragma unroll
    for (int e = 0; e < E_NUM; ++e) acc[e] = 0.f;
#pragma unroll
    for (int i = 0; i < 8; ++i) {
      const int c = lane + i * 64;                 // float4 index within row (0..511)
      float4 xv = x4[(size_t)t * 512 + c];
      ushort4 o;
      o.x = f2bf(xv.x); o.y = f2bf(xv.y); o.z = f2bf(xv.z); o.w = f2bf(xv.w);
      xb4[(size_t)t * 512 + c] = o;
#pragma unroll
      for (int e = 0; e < E_NUM; ++e) {
        float4 wv = wg1s[e * 512 + c];
        acc[e] += xv.x * wv.x + xv.y * wv.y + xv.z * wv.z + xv.w * wv.w;
      }
    }
#pragma unroll
    for (int e = 0; e < E_NUM; ++e) {
      float v = acc[e];
#pragma unroll
      for (int off = 32; off; off >>= 1) v += __shfl_xor(v, off, 64);
      acc[e] = v;
    }
    if (lane == 0) {
      float l1[E_NUM], lg[E_NUM];
#pragma unroll
      for (int e = 0; e < E_NUM; ++e) l1[e] = tanhf(acc[e]);
#pragma unroll
      for (int i = 0; i < E_NUM; ++i) {
        float s = 0.f;
#pragma unroll
        for (int e = 0; e < E_NUM; ++e) s += l1[e] * Wg2[i * E_NUM + e];
        lg[i] = s;
      }
      // stable top-2 (lowest index wins ties, like jax.lax.top_k)
      int i0 = 0; float v0 = lg[0];
#pragma unroll
      for (int i = 1; i < E_NUM; ++i) if (lg[i] > v0) { v0 = lg[i]; i0 = i; }
      int i1 = -1; float v1 = -3.4e38f;
#pragma unroll
      for (int i = 0; i < E_NUM; ++i) if (i != i0 && lg[i] > v1) { v1 = lg[i]; i1 = i; }
      float e1 = __expf(v1 - v0);
      float s0 = 1.f / (1.f + e1);
      float s1 = e1 * s0;
      eidx[t * 2] = i0; eidx[t * 2 + 1] = i1;
      scr[t * 2] = s0;  scr[t * 2 + 1] = s1;
      atomicAdd(&meta[M_CNT + i0], 1);
      atomicAdd(&meta[M_CNT + i1], 1);
    }
  }
}

// ---------------- offsets + tile map (one wave, shuffle scan) ----------------
__global__ void k_offsets(int* __restrict__ meta) {
  const int lane = threadIdx.x;
  int cnt = (lane < E_NUM) ? meta[M_CNT + lane] : 0;
  int tiles = (cnt + TILE - 1) / TILE;
  // inclusive prefix sum over lanes 0..7 (tile units)
  int pre = tiles;
#pragma unroll
  for (int off = 1; off < E_NUM; off <<= 1) {
    int v = __shfl_up(pre, off, 64);
    if (lane >= off && lane < E_NUM) pre += v;
  }
  int tb_excl = pre - tiles;               // exclusive prefix (valid lanes 0..7)
  if (lane < E_NUM) meta[M_OFF + lane] = tb_excl * TILE;
  const int nmt = __shfl(pre, E_NUM - 1, 64);
  if (lane == 0) meta[M_NMT] = nmt;
  // broadcast per-expert exclusive bases to all lanes
  int tb[E_NUM];
#pragma unroll
  for (int k = 0; k < E_NUM; ++k) tb[k] = __shfl(tb_excl, k, 64);
  for (int mt = lane; mt < nmt; mt += 64) {
    int e = 0;
#pragma unroll
    for (int k = 1; k < E_NUM; ++k) if (mt >= tb[k]) e = k;
    meta[M_TE + mt] = e;
    meta[M_TB + mt] = mt * TILE;           // tile bases are contiguous multiples of TILE
  }
}

// ---------------- compaction: (t,k) slot -> row ----------------
__global__ void k_assign(const int* __restrict__ eidx, const float* __restrict__ scr,
                         int* __restrict__ meta, int* __restrict__ rows_slot,
                         float* __restrict__ rowscore) {
  int i = blockIdx.x * blockDim.x + threadIdx.x;
  if (i >= TK_NUM) return;
  int e = eidx[i];
  int pos = atomicAdd(&meta[M_FILL + e], 1);
  int r = meta[M_OFF + e] + pos;
  rows_slot[r] = i;            // slot id (token = i>>1)
  rowscore[r] = scr[i];
}

// ---------------- grouped up-GEMM: h = silu(Xg @ Wup[e]^T + bup[e]) ----------------
// BK=64: 32 MFMA between barriers; XOR swizzle (on GLOBAL read addr) kills LDS
// bank conflicts while keeping the global_load_lds LDS destination linear.
__global__ __launch_bounds__(256) void k_up(
    const u16* __restrict__ xb, const u16* __restrict__ wupb,
    const float* __restrict__ bup, const int* __restrict__ meta,
    const int* __restrict__ rows_slot, u16* __restrict__ hbuf) {
  const int mt = blockIdx.y;
  if (mt >= meta[M_NMT]) return;
  const int e = meta[M_TE + mt];
  const int mbase = meta[M_TB + mt];
  const int nt = blockIdx.x;

  __shared__ u16 As[TILE * BK];
  __shared__ u16 Bs[TILE * BK];

  const int tid = threadIdx.x;
  const int lane = tid & 63;
  const int w = tid >> 6;
  const int r0 = tid >> 3;                               // staged row 0..31
  const int cb = (((tid & 7) ^ ((tid >> 3) & 7)) * 8);   // swizzled k-chunk

  const u16* gA[4];
  const u16* gB[4];
#pragma unroll
  for (int j = 0; j < 4; ++j) {
    int s = rows_slot[mbase + r0 + 32 * j]; if (s < 0) s = 0;
    gA[j] = xb + (size_t)(s >> 1) * D_DIM + cb;
    gB[j] = wupb + ((size_t)e * HE_DIM + nt * TILE + r0 + 32 * j) * D_DIM + cb;
  }
  u16* lA = As + tid * 8;
  u16* lB = Bs + tid * 8;

  const int wm = (w & 1) * 64;
  const int wn = (w >> 1) * 64;
  const int quad = lane >> 4;
  const int l16 = lane & 15;
  const int sw = l16 & 7;
  const u16* pa0 = As + (wm + l16) * BK;
  const u16* pb0 = Bs + (wn + l16) * BK;

  f32x4 acc[4][4] = {};

  for (int k0 = 0; k0 < D_DIM; k0 += BK) {
#pragma unroll
    for (int j = 0; j < 4; ++j) gload16(gA[j] + k0, lA + 2048 * j);
#pragma unroll
    for (int j = 0; j < 4; ++j) gload16(gB[j] + k0, lB + 2048 * j);
    __syncthreads();
#pragma unroll
    for (int h = 0; h < 2; ++h) {
      const int off = ((h * 4 + quad) ^ sw) * 8;
      bf16x8 af[4], bfr[4];
#pragma unroll
      for (int i = 0; i < 4; ++i) {
        af[i]  = *(const bf16x8*)(pa0 + i * 16 * BK + off);
        bfr[i] = *(const bf16x8*)(pb0 + i * 16 * BK + off);
      }
#pragma unroll
      for (int mi = 0; mi < 4; ++mi)
#pragma unroll
        for (int ni = 0; ni < 4; ++ni)
          acc[mi][ni] = __builtin_amdgcn_mfma_f32_16x16x32_bf16(af[mi], bfr[ni], acc[mi][ni], 0, 0, 0);
    }
    __syncthreads();
  }

#pragma unroll
  for (int mi = 0; mi < 4; ++mi) {
    const int m = wm + mi * 16 + quad * 4;
#pragma unroll
    for (int ni = 0; ni < 4; ++ni) {
      const int ng = nt * TILE + wn + ni * 16 + l16;
      const float bias = bup[e * HE_DIM + ng];
#pragma unroll
      for (int r = 0; r < 4; ++r) {
        float v = acc[mi][ni][r] + bias;
        v = v / (1.0f + __expf(-v));     // silu
        hbuf[(size_t)(mbase + m + r) * HE_DIM + ng] = f2bf(v);
      }
    }
  }
}

// ---------------- grouped down-GEMM: slot[s] = score * (h @ Wdown[e]^T + bdown[e]) ----------------
__global__ __launch_bounds__(256) void k_down(
    const u16* __restrict__ hbuf, const u16* __restrict__ wdnb,
    const float* __restrict__ bdown, const int* __restrict__ meta,
    const int* __restrict__ rows_slot, const float* __restrict__ rowscore,
    u16* __restrict__ slot) {
  const int mt = blockIdx.y;
  if (mt >= meta[M_NMT]) return;
  const int e = meta[M_TE + mt];
  const int mbase = meta[M_TB + mt];
  const int nt = blockIdx.x;

  __shared__ u16 As[TILE * BK];
  __shared__ u16 Bs[TILE * BK];

  const int tid = threadIdx.x;
  const int lane = tid & 63;
  const int w = tid >> 6;
  const int r0 = tid >> 3;
  const int cb = (((tid & 7) ^ ((tid >> 3) & 7)) * 8);

  const u16* gA[4];
  const u16* gB[4];
#pragma unroll
  for (int j = 0; j < 4; ++j) {
    gA[j] = hbuf + (size_t)(mbase + r0 + 32 * j) * HE_DIM + cb;
    gB[j] = wdnb + ((size_t)e * D_DIM + nt * TILE + r0 + 32 * j) * HE_DIM + cb;
  }
  u16* lA = As + tid * 8;
  u16* lB = Bs + tid * 8;

  const int wm = (w & 1) * 64;
  const int wn = (w >> 1) * 64;
  const int quad = lane >> 4;
  const int l16 = lane & 15;
  const int sw = l16 & 7;
  const u16* pa0 = As + (wm + l16) * BK;
  const u16* pb0 = Bs + (wn + l16) * BK;

  f32x4 acc[4][4] = {};

  for (int k0 = 0; k0 < HE_DIM; k0 += BK) {
#pragma unroll
    for (int j = 0; j < 4; ++j) gload16(gA[j] + k0, lA + 2048 * j);
#pragma unroll
    for (int j = 0; j < 4; ++j) gload16(gB[j] + k0, lB + 2048 * j);
    __syncthreads();
#pragma unroll
    for (int h = 0; h < 2; ++h) {
      const int off = ((h * 4 + quad) ^ sw) * 8;
      bf16x8 af[4], bfr[4];
#pragma unroll
      for (int i = 0; i < 4; ++i) {
        af[i]  = *(const bf16x8*)(pa0 + i * 16 * BK + off);
        bfr[i] = *(const bf16x8*)(pb0 + i * 16 * BK + off);
      }
#pragma unroll
      for (int mi = 0; mi < 4; ++mi)
#pragma unroll
        for (int ni = 0; ni < 4; ++ni)
          acc[mi][ni] = __builtin_amdgcn_mfma_f32_16x16x32_bf16(af[mi], bfr[ni], acc[mi][ni], 0, 0, 0);
    }
    __syncthreads();
  }

#pragma unroll
  for (int mi = 0; mi < 4; ++mi) {
    const int m = wm + mi * 16 + quad * 4;
#pragma unroll
    for (int r = 0; r < 4; ++r) {
      const int rg = mbase + m + r;
      const int s = rows_slot[rg];
      const float sc = rowscore[rg];
      if (s < 0) continue;               // padding row
      u16* dst = slot + (size_t)s * D_DIM;
#pragma unroll
      for (int ni = 0; ni < 4; ++ni) {
        const int ng = nt * TILE + wn + ni * 16 + l16;
        float v = (acc[mi][ni][r] + bdown[e * D_DIM + ng]) * sc;
        dst[ng] = f2bf(v);
      }
    }
  }
}

// ---------------- combine: out[t] = slot[t][0] + slot[t][1] (fully coalesced) ----------------
__global__ __launch_bounds__(256) void k_combine(const u16* __restrict__ slot,
                                                 float* __restrict__ out) {
  int i = blockIdx.x * blockDim.x + threadIdx.x;   // one 16B chunk (8 bf16) per thread
  int t = i >> 8;                                  // D/8 = 256 chunks per token
  int c = i & 255;
  const uint4* p0 = (const uint4*)(slot + (size_t)(t * 2) * D_DIM) + c;
  const uint4* p1 = (const uint4*)(slot + (size_t)(t * 2 + 1) * D_DIM) + c;
  uint4 a = *p0, b = *p1;
  float4 o0, o1;
  o0.x = bf_lo(a.x) + bf_lo(b.x);  o0.y = bf_hi(a.x) + bf_hi(b.x);
  o0.z = bf_lo(a.y) + bf_lo(b.y);  o0.w = bf_hi(a.y) + bf_hi(b.y);
  o1.x = bf_lo(a.z) + bf_lo(b.z);  o1.y = bf_hi(a.z) + bf_hi(b.z);
  o1.z = bf_lo(a.w) + bf_lo(b.w);  o1.w = bf_hi(a.w) + bf_hi(b.w);
  float4* po = (float4*)(out + (size_t)t * D_DIM) + c * 2;
  po[0] = o0;
  po[1] = o1;
}

// ---------------- launcher ----------------
extern "C" void kernel_launch(void* const* d_in, const int* in_sizes, int n_in,
                              void* d_out, int out_size, void* d_ws, size_t ws_size,
                              hipStream_t stream) {
  const float* x     = (const float*)d_in[0];
  const float* Wg1   = (const float*)d_in[1];
  const float* Wg2   = (const float*)d_in[2];
  const float* Wup   = (const float*)d_in[3];
  const float* bup   = (const float*)d_in[4];
  const float* Wdown = (const float*)d_in[5];
  const float* bdown = (const float*)d_in[6];
  float* out = (float*)d_out;

  char* ws = (char*)d_ws;
  u16*   xb         = (u16*)(ws + OFF_XB);
  u16*   wupb       = (u16*)(ws + OFF_WUPB);
  u16*   wdnb       = (u16*)(ws + OFF_WDNB);
  u16*   hbuf       = (u16*)(ws + OFF_H);
  u16*   slotbuf    = (u16*)(ws + OFF_SLOT);
  float* scr        = (float*)(ws + OFF_SCR);
  int*   eidx       = (int*)(ws + OFF_EIDX);
  int*   rows_slot  = (int*)(ws + OFF_RT);
  float* rowscore   = (float*)(ws + OFF_RS);
  int*   meta       = (int*)(ws + OFF_META);

  k_init<<<(MAXROWS + 255) / 256, 256, 0, stream>>>(meta, rows_slot, rowscore);
  k_cvt2<<<8192, 256, 0, stream>>>((const float4*)Wup, (const float4*)Wdown,
                                   (ushort4*)wupb, (ushort4*)wdnb,
                                   E_NUM * HE_DIM * D_DIM / 4);
  k_gate<<<T_NUM / 16, 256, 0, stream>>>((const float4*)x, (const float4*)Wg1, Wg2,
                                         (ushort4*)xb, eidx, scr, meta);
  k_offsets<<<1, 64, 0, stream>>>(meta);
  k_assign<<<TK_NUM / 256, 256, 0, stream>>>(eidx, scr, meta, rows_slot, rowscore);
  k_up<<<dim3(HE_DIM / TILE, MAXMT), 256, 0, stream>>>(xb, wupb, bup, meta, rows_slot, hbuf);
  k_down<<<dim3(D_DIM / TILE, MAXMT), 256, 0, stream>>>(hbuf, wdnb, bdown, meta,
                                                        rows_slot, rowscore, slotbuf);
  k_combine<<<T_NUM * D_DIM / 8 / 256, 256, 0, stream>>>(slotbuf, out);
}

// Round 4
// 379.916 us; speedup vs baseline: 1.4703x; 1.2671x over previous
//
#include <hip/hip_runtime.h>
#include <hip/hip_bf16.h>

// ---------------- problem constants ----------------
#define D_DIM 2048
#define HE_DIM 1024
#define E_NUM 8
#define T_NUM 4096
#define TK_NUM 8192           // T * K (top-2)
#define TILE 128              // GEMM M/N tile
#define BK 64                 // GEMM K tile (two 16x16x32 MFMA deep -> 32 MFMA/barrier)
#define MAXROWS 9216          // TK + E*TILE padding
#define MAXMT 72              // max M-tiles: 64 + 8

// meta (int) layout in workspace — counters padded to 128 B (32 ints) so each
// expert's atomic counter lives on its own cache line (kills same-line
// serialization at the device coherence point).
#define M_CNT(e)  ((e) * 32)          // [0,256)   per-expert token count
#define M_FILL(e) (256 + (e) * 32)    // [256,512) atomic fill cursor
#define M_OFF  512                    // [8] padded row base per expert
#define M_NMT  520                    // [1] number of m-tiles
#define M_TE   528                    // [72] m-tile -> expert
#define M_TB   600                    // [72] m-tile -> global row base
#define M_INTS 1024

typedef unsigned short u16;
typedef __attribute__((ext_vector_type(8))) short bf16x8;  // 8 bf16 in 4 VGPRs
typedef __attribute__((ext_vector_type(4))) float f32x4;

// workspace offsets (bytes)
// xb [0,16M) and wupb [16M,48M) are dead after k_up; slot [T][2][D] bf16 (33.5M)
// overlaps them (k_down/k_combine run strictly after k_up on the stream).
#define OFF_XB   ((size_t)0)                                     // [T][D] bf16  16 MB
#define OFF_WUPB (OFF_XB + (size_t)T_NUM * D_DIM * 2)            // [E][HE][D] bf16 32 MB
#define OFF_SLOT ((size_t)0)                                     // [T][2][D] bf16 33.5 MB (overlap)
#define OFF_WDNB (OFF_WUPB + (size_t)E_NUM * HE_DIM * D_DIM * 2) // [E][D][HE] bf16 32 MB
#define OFF_H    (OFF_WDNB + (size_t)E_NUM * D_DIM * HE_DIM * 2) // [MAXROWS][HE] bf16 18.9 MB
#define OFF_SCR  (OFF_H + (size_t)MAXROWS * HE_DIM * 2)          // [TK] f32 slot score
#define OFF_EIDX (OFF_SCR + (size_t)TK_NUM * 4)                  // [TK] int slot expert
#define OFF_RT   (OFF_EIDX + (size_t)TK_NUM * 4)                 // [MAXROWS] int row->slot id
#define OFF_RS   (OFF_RT + (size_t)MAXROWS * 4)                  // [MAXROWS] f32 row score
#define OFF_META (OFF_RS + (size_t)MAXROWS * 4)                  // ints

__device__ __forceinline__ u16 f2bf(float f) {
  unsigned u = __float_as_uint(f);
  u += 0x7FFFu + ((u >> 16) & 1u);   // round-to-nearest-even
  return (u16)(u >> 16);
}
__device__ __forceinline__ float bf_lo(unsigned u) { return __uint_as_float(u << 16); }
__device__ __forceinline__ float bf_hi(unsigned u) { return __uint_as_float(u & 0xFFFF0000u); }

__device__ __forceinline__ void gload16(const void* g, void* l) {
  // async global->LDS, 16B per lane; LDS dest = wave-uniform base + lane*16
  __builtin_amdgcn_global_load_lds((const __attribute__((address_space(1))) void*)g,
                                   (__attribute__((address_space(3))) void*)l,
                                   16, 0, 0);
}

// ---------------- init: meta zero, rows poisoned to "padding" ----------------
__global__ void k_init(int* __restrict__ meta, int* __restrict__ rows_slot,
                       float* __restrict__ rowscore) {
  int i = blockIdx.x * blockDim.x + threadIdx.x;
  if (i < M_INTS) meta[i] = 0;
  if (i < MAXROWS) { rows_slot[i] = -1; rowscore[i] = 0.0f; }
}

// ---------------- f32 -> bf16 weight conversion (both weights, one launch) ----------------
__global__ void k_cvt2(const float4* __restrict__ s1, const float4* __restrict__ s2,
                       ushort4* __restrict__ d1, ushort4* __restrict__ d2, int n4) {
  int i = blockIdx.x * blockDim.x + threadIdx.x;
  int st = gridDim.x * blockDim.x;
  for (; i < 2 * n4; i += st) {
    const float4* s = (i < n4) ? s1 : s2;
    ushort4* d = (i < n4) ? d1 : d2;
    int j = (i < n4) ? i : i - n4;
    float4 v = s[j];
    ushort4 o;
    o.x = f2bf(v.x); o.y = f2bf(v.y); o.z = f2bf(v.z); o.w = f2bf(v.w);
    d[j] = o;
  }
}

// ---------------- gate: Wg1 in LDS, LDS count histogram, padded global atomics ----------------
__global__ __launch_bounds__(256) void k_gate(
    const float4* __restrict__ x4, const float4* __restrict__ Wg1_4,
    const float* __restrict__ Wg2, ushort4* __restrict__ xb4,
    int* __restrict__ eidx, float* __restrict__ scr, int* __restrict__ meta) {
  __shared__ float4 wg1s[E_NUM * (D_DIM / 4)];   // 8*512*16B = 64 KB
  __shared__ int cnt_s[E_NUM];
  const int tid = threadIdx.x;
  if (tid < E_NUM) cnt_s[tid] = 0;
#pragma unroll
  for (int i = 0; i < 16; ++i) wg1s[tid + i * 256] = Wg1_4[tid + i * 256];
  __syncthreads();

  const int w = tid >> 6;
  const int lane = tid & 63;
  for (int j = 0; j < 4; ++j) {
    const int t = blockIdx.x * 16 + w * 4 + j;
    float acc[E_NUM];
#pragma unroll
    for (int e = 0; e < E_NUM; ++e) acc[e] = 0.f;
#pragma unroll
    for (int i = 0; i < 8; ++i) {
      const int c = lane + i * 64;                 // float4 index within row (0..511)
      float4 xv = x4[(size_t)t * 512 + c];
      ushort4 o;
      o.x = f2bf(xv.x); o.y = f2bf(xv.y); o.z = f2bf(xv.z); o.w = f2bf(xv.w);
      xb4[(size_t)t * 512 + c] = o;
#pragma unroll
      for (int e = 0; e < E_NUM; ++e) {
        float4 wv = wg1s[e * 512 + c];
        acc[e] += xv.x * wv.x + xv.y * wv.y + xv.z * wv.z + xv.w * wv.w;
      }
    }
#pragma unroll
    for (int e = 0; e < E_NUM; ++e) {
      float v = acc[e];
#pragma unroll
      for (int off = 32; off; off >>= 1) v += __shfl_xor(v, off, 64);
      acc[e] = v;
    }
    if (lane == 0) {
      float l1[E_NUM], lg[E_NUM];
#pragma unroll
      for (int e = 0; e < E_NUM; ++e) l1[e] = tanhf(acc[e]);
#pragma unroll
      for (int i = 0; i < E_NUM; ++i) {
        float s = 0.f;
#pragma unroll
        for (int e = 0; e < E_NUM; ++e) s += l1[e] * Wg2[i * E_NUM + e];
        lg[i] = s;
      }
      // stable top-2 (lowest index wins ties, like jax.lax.top_k)
      int i0 = 0; float v0 = lg[0];
#pragma unroll
      for (int i = 1; i < E_NUM; ++i) if (lg[i] > v0) { v0 = lg[i]; i0 = i; }
      int i1 = -1; float v1 = -3.4e38f;
#pragma unroll
      for (int i = 0; i < E_NUM; ++i) if (i != i0 && lg[i] > v1) { v1 = lg[i]; i1 = i; }
      float e1 = __expf(v1 - v0);
      float s0 = 1.f / (1.f + e1);
      float s1 = e1 * s0;
      eidx[t * 2] = i0; eidx[t * 2 + 1] = i1;
      scr[t * 2] = s0;  scr[t * 2 + 1] = s1;
      atomicAdd(&cnt_s[i0], 1);      // LDS atomic — block-local, cheap
      atomicAdd(&cnt_s[i1], 1);
    }
  }
  __syncthreads();
  if (tid < E_NUM) atomicAdd(&meta[M_CNT(tid)], cnt_s[tid]);  // 8/block, padded lines
}

// ---------------- offsets + tile map (one wave, shuffle scan) ----------------
__global__ void k_offsets(int* __restrict__ meta) {
  const int lane = threadIdx.x;
  int cnt = (lane < E_NUM) ? meta[M_CNT(lane)] : 0;
  int tiles = (cnt + TILE - 1) / TILE;
  // inclusive prefix sum over lanes 0..7 (tile units)
  int pre = tiles;
#pragma unroll
  for (int off = 1; off < E_NUM; off <<= 1) {
    int v = __shfl_up(pre, off, 64);
    if (lane >= off && lane < E_NUM) pre += v;
  }
  int tb_excl = pre - tiles;               // exclusive prefix (valid lanes 0..7)
  if (lane < E_NUM) meta[M_OFF + lane] = tb_excl * TILE;
  const int nmt = __shfl(pre, E_NUM - 1, 64);
  if (lane == 0) meta[M_NMT] = nmt;
  // broadcast per-expert exclusive bases to all lanes
  int tb[E_NUM];
#pragma unroll
  for (int k = 0; k < E_NUM; ++k) tb[k] = __shfl(tb_excl, k, 64);
  for (int mt = lane; mt < nmt; mt += 64) {
    int e = 0;
#pragma unroll
    for (int k = 1; k < E_NUM; ++k) if (mt >= tb[k]) e = k;
    meta[M_TE + mt] = e;
    meta[M_TB + mt] = mt * TILE;           // tile bases are contiguous multiples of TILE
  }
}

// ---------------- compaction: wave-aggregated fetch-add ----------------
__global__ void k_assign(const int* __restrict__ eidx, const float* __restrict__ scr,
                         int* __restrict__ meta, int* __restrict__ rows_slot,
                         float* __restrict__ rowscore) {
  int i = blockIdx.x * blockDim.x + threadIdx.x;
  const int lane = threadIdx.x & 63;
  int e = eidx[i];
  int pos = 0;
#pragma unroll
  for (int ex = 0; ex < E_NUM; ++ex) {
    unsigned long long m = __ballot(e == ex);
    if (e == ex) {
      int leader = __ffsll((long long)m) - 1;
      int rank = __popcll(m & ((1ull << lane) - 1ull));
      int b = 0;
      if (lane == leader) b = atomicAdd(&meta[M_FILL(ex)], __popcll(m));
      b = __shfl(b, leader, 64);
      pos = b + rank;
    }
  }
  int r = meta[M_OFF + e] + pos;
  rows_slot[r] = i;            // slot id (token = i>>1)
  rowscore[r] = scr[i];
}

// ---------------- grouped up-GEMM: h = silu(Xg @ Wup[e]^T + bup[e]) ----------------
// BK=64: 32 MFMA between barriers; XOR swizzle (on GLOBAL read addr) kills LDS
// bank conflicts while keeping the global_load_lds LDS destination linear.
__global__ __launch_bounds__(256) void k_up(
    const u16* __restrict__ xb, const u16* __restrict__ wupb,
    const float* __restrict__ bup, const int* __restrict__ meta,
    const int* __restrict__ rows_slot, u16* __restrict__ hbuf) {
  const int mt = blockIdx.y;
  if (mt >= meta[M_NMT]) return;
  const int e = meta[M_TE + mt];
  const int mbase = meta[M_TB + mt];
  const int nt = blockIdx.x;

  __shared__ u16 As[TILE * BK];
  __shared__ u16 Bs[TILE * BK];

  const int tid = threadIdx.x;
  const int lane = tid & 63;
  const int w = tid >> 6;
  const int r0 = tid >> 3;                               // staged row 0..31
  const int cb = (((tid & 7) ^ ((tid >> 3) & 7)) * 8);   // swizzled k-chunk

  const u16* gA[4];
  const u16* gB[4];
#pragma unroll
  for (int j = 0; j < 4; ++j) {
    int s = rows_slot[mbase + r0 + 32 * j]; if (s < 0) s = 0;
    gA[j] = xb + (size_t)(s >> 1) * D_DIM + cb;
    gB[j] = wupb + ((size_t)e * HE_DIM + nt * TILE + r0 + 32 * j) * D_DIM + cb;
  }
  u16* lA = As + tid * 8;
  u16* lB = Bs + tid * 8;

  const int wm = (w & 1) * 64;
  const int wn = (w >> 1) * 64;
  const int quad = lane >> 4;
  const int l16 = lane & 15;
  const int sw = l16 & 7;
  const u16* pa0 = As + (wm + l16) * BK;
  const u16* pb0 = Bs + (wn + l16) * BK;

  f32x4 acc[4][4] = {};

  for (int k0 = 0; k0 < D_DIM; k0 += BK) {
#pragma unroll
    for (int j = 0; j < 4; ++j) gload16(gA[j] + k0, lA + 2048 * j);
#pragma unroll
    for (int j = 0; j < 4; ++j) gload16(gB[j] + k0, lB + 2048 * j);
    __syncthreads();
#pragma unroll
    for (int h = 0; h < 2; ++h) {
      const int off = ((h * 4 + quad) ^ sw) * 8;
      bf16x8 af[4], bfr[4];
#pragma unroll
      for (int i = 0; i < 4; ++i) {
        af[i]  = *(const bf16x8*)(pa0 + i * 16 * BK + off);
        bfr[i] = *(const bf16x8*)(pb0 + i * 16 * BK + off);
      }
#pragma unroll
      for (int mi = 0; mi < 4; ++mi)
#pragma unroll
        for (int ni = 0; ni < 4; ++ni)
          acc[mi][ni] = __builtin_amdgcn_mfma_f32_16x16x32_bf16(af[mi], bfr[ni], acc[mi][ni], 0, 0, 0);
    }
    __syncthreads();
  }

#pragma unroll
  for (int mi = 0; mi < 4; ++mi) {
    const int m = wm + mi * 16 + quad * 4;
#pragma unroll
    for (int ni = 0; ni < 4; ++ni) {
      const int ng = nt * TILE + wn + ni * 16 + l16;
      const float bias = bup[e * HE_DIM + ng];
#pragma unroll
      for (int r = 0; r < 4; ++r) {
        float v = acc[mi][ni][r] + bias;
        v = v / (1.0f + __expf(-v));     // silu
        hbuf[(size_t)(mbase + m + r) * HE_DIM + ng] = f2bf(v);
      }
    }
  }
}

// ---------------- grouped down-GEMM: slot[s] = score * (h @ Wdown[e]^T + bdown[e]) ----------------
__global__ __launch_bounds__(256) void k_down(
    const u16* __restrict__ hbuf, const u16* __restrict__ wdnb,
    const float* __restrict__ bdown, const int* __restrict__ meta,
    const int* __restrict__ rows_slot, const float* __restrict__ rowscore,
    u16* __restrict__ slot) {
  const int mt = blockIdx.y;
  if (mt >= meta[M_NMT]) return;
  const int e = meta[M_TE + mt];
  const int mbase = meta[M_TB + mt];
  const int nt = blockIdx.x;

  __shared__ u16 As[TILE * BK];
  __shared__ u16 Bs[TILE * BK];

  const int tid = threadIdx.x;
  const int lane = tid & 63;
  const int w = tid >> 6;
  const int r0 = tid >> 3;
  const int cb = (((tid & 7) ^ ((tid >> 3) & 7)) * 8);

  const u16* gA[4];
  const u16* gB[4];
#pragma unroll
  for (int j = 0; j < 4; ++j) {
    gA[j] = hbuf + (size_t)(mbase + r0 + 32 * j) * HE_DIM + cb;
    gB[j] = wdnb + ((size_t)e * D_DIM + nt * TILE + r0 + 32 * j) * HE_DIM + cb;
  }
  u16* lA = As + tid * 8;
  u16* lB = Bs + tid * 8;

  const int wm = (w & 1) * 64;
  const int wn = (w >> 1) * 64;
  const int quad = lane >> 4;
  const int l16 = lane & 15;
  const int sw = l16 & 7;
  const u16* pa0 = As + (wm + l16) * BK;
  const u16* pb0 = Bs + (wn + l16) * BK;

  f32x4 acc[4][4] = {};

  for (int k0 = 0; k0 < HE_DIM; k0 += BK) {
#pragma unroll
    for (int j = 0; j < 4; ++j) gload16(gA[j] + k0, lA + 2048 * j);
#pragma unroll
    for (int j = 0; j < 4; ++j) gload16(gB[j] + k0, lB + 2048 * j);
    __syncthreads();
#pragma unroll
    for (int h = 0; h < 2; ++h) {
      const int off = ((h * 4 + quad) ^ sw) * 8;
      bf16x8 af[4], bfr[4];
#pragma unroll
      for (int i = 0; i < 4; ++i) {
        af[i]  = *(const bf16x8*)(pa0 + i * 16 * BK + off);
        bfr[i] = *(const bf16x8*)(pb0 + i * 16 * BK + off);
      }
#pragma unroll
      for (int mi = 0; mi < 4; ++mi)
#pragma unroll
        for (int ni = 0; ni < 4; ++ni)
          acc[mi][ni] = __builtin_amdgcn_mfma_f32_16x16x32_bf16(af[mi], bfr[ni], acc[mi][ni], 0, 0, 0);
    }
    __syncthreads();
  }

#pragma unroll
  for (int mi = 0; mi < 4; ++mi) {
    const int m = wm + mi * 16 + quad * 4;
#pragma unroll
    for (int r = 0; r < 4; ++r) {
      const int rg = mbase + m + r;
      const int s = rows_slot[rg];
      const float sc = rowscore[rg];
      if (s < 0) continue;               // padding row
      u16* dst = slot + (size_t)s * D_DIM;
#pragma unroll
      for (int ni = 0; ni < 4; ++ni) {
        const int ng = nt * TILE + wn + ni * 16 + l16;
        float v = (acc[mi][ni][r] + bdown[e * D_DIM + ng]) * sc;
        dst[ng] = f2bf(v);
      }
    }
  }
}

// ---------------- combine: out[t] = slot[t][0] + slot[t][1] (fully coalesced) ----------------
__global__ __launch_bounds__(256) void k_combine(const u16* __restrict__ slot,
                                                 float* __restrict__ out) {
  int i = blockIdx.x * blockDim.x + threadIdx.x;   // one 16B chunk (8 bf16) per thread
  int t = i >> 8;                                  // D/8 = 256 chunks per token
  int c = i & 255;
  const uint4* p0 = (const uint4*)(slot + (size_t)(t * 2) * D_DIM) + c;
  const uint4* p1 = (const uint4*)(slot + (size_t)(t * 2 + 1) * D_DIM) + c;
  uint4 a = *p0, b = *p1;
  float4 o0, o1;
  o0.x = bf_lo(a.x) + bf_lo(b.x);  o0.y = bf_hi(a.x) + bf_hi(b.x);
  o0.z = bf_lo(a.y) + bf_lo(b.y);  o0.w = bf_hi(a.y) + bf_hi(b.y);
  o1.x = bf_lo(a.z) + bf_lo(b.z);  o1.y = bf_hi(a.z) + bf_hi(b.z);
  o1.z = bf_lo(a.w) + bf_lo(b.w);  o1.w = bf_hi(a.w) + bf_hi(b.w);
  float4* po = (float4*)(out + (size_t)t * D_DIM) + c * 2;
  po[0] = o0;
  po[1] = o1;
}

// ---------------- launcher ----------------
extern "C" void kernel_launch(void* const* d_in, const int* in_sizes, int n_in,
                              void* d_out, int out_size, void* d_ws, size_t ws_size,
                              hipStream_t stream) {
  const float* x     = (const float*)d_in[0];
  const float* Wg1   = (const float*)d_in[1];
  const float* Wg2   = (const float*)d_in[2];
  const float* Wup   = (const float*)d_in[3];
  const float* bup   = (const float*)d_in[4];
  const float* Wdown = (const float*)d_in[5];
  const float* bdown = (const float*)d_in[6];
  float* out = (float*)d_out;

  char* ws = (char*)d_ws;
  u16*   xb         = (u16*)(ws + OFF_XB);
  u16*   wupb       = (u16*)(ws + OFF_WUPB);
  u16*   wdnb       = (u16*)(ws + OFF_WDNB);
  u16*   hbuf       = (u16*)(ws + OFF_H);
  u16*   slotbuf    = (u16*)(ws + OFF_SLOT);
  float* scr        = (float*)(ws + OFF_SCR);
  int*   eidx       = (int*)(ws + OFF_EIDX);
  int*   rows_slot  = (int*)(ws + OFF_RT);
  float* rowscore   = (float*)(ws + OFF_RS);
  int*   meta       = (int*)(ws + OFF_META);

  k_init<<<(MAXROWS + 255) / 256, 256, 0, stream>>>(meta, rows_slot, rowscore);
  k_cvt2<<<8192, 256, 0, stream>>>((const float4*)Wup, (const float4*)Wdown,
                                   (ushort4*)wupb, (ushort4*)wdnb,
                                   E_NUM * HE_DIM * D_DIM / 4);
  k_gate<<<T_NUM / 16, 256, 0, stream>>>((const float4*)x, (const float4*)Wg1, Wg2,
                                         (ushort4*)xb, eidx, scr, meta);
  k_offsets<<<1, 64, 0, stream>>>(meta);
  k_assign<<<TK_NUM / 256, 256, 0, stream>>>(eidx, scr, meta, rows_slot, rowscore);
  k_up<<<dim3(HE_DIM / TILE, MAXMT), 256, 0, stream>>>(xb, wupb, bup, meta, rows_slot, hbuf);
  k_down<<<dim3(D_DIM / TILE, MAXMT), 256, 0, stream>>>(hbuf, wdnb, bdown, meta,
                                                        rows_slot, rowscore, slotbuf);
  k_combine<<<T_NUM * D_DIM / 8 / 256, 256, 0, stream>>>(slotbuf, out);
}